// Round 11
// 10797.414 us; speedup vs baseline: 1.8550x; 1.8550x over previous
//
#include <hip/hip_runtime.h>
#include <hip/hip_bf16.h>

// Problem constants
constexpr int NB   = 32;    // batch
constexpr int NT   = 512;   // tokens
constexpr int ND   = 768;   // bert dim
constexpr int NW   = 255;   // words
constexpr int NH   = 768;   // lstm hidden
constexpr int NCLS = 9;     // NER classes
constexpr int NMTOT = NB * NW;          // 8160 rows
constexpr int NG4  = 4 * NH;            // 3072 gate dim
constexpr int PARSZ = NH * NB;          // 24576 floats per h parity buffer
constexpr int KR   = NH / 4;            // 192 k per k-quarter

__device__ __forceinline__ float sigmoidf_(float x) {
    return 1.0f / (1.0f + expf(-x));
}

// ---------------------------------------------------------------------------
// Kernel 1 (ROUND-0 VERBATIM): first-subword index per (b, w).
// rowbase[m] for m = b*NW + w.
// ---------------------------------------------------------------------------
__global__ void pool_idx_kernel(const int* __restrict__ word_ids,
                                int* __restrict__ rowbase) {
    int bb = blockIdx.x;
    int w = threadIdx.x;
    if (w >= NW) return;
    const int* row = word_ids + bb * NT;
    int ft = 0;
    for (int t = 0; t < NT; ++t) {
        if (row[t] == w) { ft = t; break; }
    }
    rowbase[bb * NW + w] = (bb * NT + ft) * ND;
}

// ---------------------------------------------------------------------------
// Kernel 2 (ROUND-0 VERBATIM): xg[dir] = pooled @ W_ih[dir]^T + b[dir] (f32)
// Row-major output xg[m][4H], m = b*NW + w.
// ---------------------------------------------------------------------------
__global__ __launch_bounds__(256) void gemm_xg_kernel(
    const float* __restrict__ bert, const int* __restrict__ rowbase,
    const float* __restrict__ Wf, const float* __restrict__ biasf,
    const float* __restrict__ Wb, const float* __restrict__ biasb,
    float* __restrict__ xgf, float* __restrict__ xgb) {
    const int dir = blockIdx.z;
    const float* Wt = dir ? Wb : Wf;
    const float* bias = dir ? biasb : biasf;
    float* xg = dir ? xgb : xgf;
    const int m0 = blockIdx.y * 128;
    const int n0 = blockIdx.x * 128;

    __shared__ float As[8][128];
    __shared__ float Bs[8][128];

    const int t = threadIdx.x;
    const int lrow = t >> 1;        // 0..127
    const int lk = (t & 1) * 4;     // 0 or 4

    int am = m0 + lrow;
    const float* aptr = bert + (am < NMTOT ? rowbase[am] : rowbase[NMTOT - 1]) + lk;
    const float* bptr = Wt + (size_t)(n0 + lrow) * ND + lk;

    const int tm = (t & 15) * 8;
    const int tn = (t >> 4) * 8;

    float acc[8][8] = {};

    for (int k0 = 0; k0 < ND; k0 += 8) {
        float4 av = *(const float4*)(aptr + k0);
        float4 bv = *(const float4*)(bptr + k0);
        __syncthreads();
        As[lk + 0][lrow] = av.x; As[lk + 1][lrow] = av.y;
        As[lk + 2][lrow] = av.z; As[lk + 3][lrow] = av.w;
        Bs[lk + 0][lrow] = bv.x; Bs[lk + 1][lrow] = bv.y;
        Bs[lk + 2][lrow] = bv.z; Bs[lk + 3][lrow] = bv.w;
        __syncthreads();
#pragma unroll
        for (int kk = 0; kk < 8; ++kk) {
            float ar[8], br[8];
#pragma unroll
            for (int i = 0; i < 8; ++i) ar[i] = As[kk][tm + i];
#pragma unroll
            for (int j = 0; j < 8; ++j) br[j] = Bs[kk][tn + j];
#pragma unroll
            for (int i = 0; i < 8; ++i)
#pragma unroll
                for (int j = 0; j < 8; ++j)
                    acc[i][j] = fmaf(ar[i], br[j], acc[i][j]);
        }
    }

#pragma unroll
    for (int i = 0; i < 8; ++i) {
        int m = m0 + tm + i;
        if (m >= NMTOT) continue;
        float* orow = xg + (size_t)m * NG4 + n0 + tn;
#pragma unroll
        for (int j = 0; j < 8; ++j) orow[j] = acc[i][j] + bias[n0 + tn + j];
    }
}

// ---------------------------------------------------------------------------
// Kernel 3: ONE LSTM time step, launched 255 times sequentially.
// NO cooperative launch, NO grid.sync, NO LDS — the kernel boundary is the
// grid-wide barrier (full device coherence between dependent dispatches).
// 256 blocks x 192 threads. Block: dir = blk>>7, cb = blk&127 -> cols
// cb*6..cb*6+5. Thread t: ci = t>>5 (local col 0..5), ks = (t>>3)&3
// (k quarter), lbq = t&7 (batch quad -> lb = lbq*4..+3).
// Each thread: 4-gate partial dot over its 192-k quarter for 4 batches
// (weights + h as float4 straight from L2); partials combined across ks with
// __shfl_xor(8/16) (lane bits 3..4 = ks); ks==0 lanes load xg + c, apply
// activations, store h (parity (s+1)&1, layout [b][k]), hout, and c.
// ---------------------------------------------------------------------------
__global__ __launch_bounds__(192) void lstm_step_kernel(
    const int s,
    const float* __restrict__ xgf, const float* __restrict__ xgb,
    const float* __restrict__ Whf, const float* __restrict__ Whb,
    float* __restrict__ hf_out, float* __restrict__ hb_out,
    float* __restrict__ hbuf /* [2 dir][2 par][PARSZ] */,
    float* __restrict__ cst  /* [2 dir][PARSZ] */) {
    const int blk = blockIdx.x;       // 0..255
    const int dir = blk >> 7;
    const int cb = blk & 127;
    const int t = threadIdx.x;        // 0..191
    const int ci = t >> 5;            // 0..5 local col
    const int ks = (t >> 3) & 3;      // 0..3 k quarter
    const int lbq = t & 7;            // 0..7 batch quad
    const int col = cb * 6 + ci;
    const int lb0 = lbq * 4;
    const int ksk = ks * KR;          // k-quarter base

    const float* Wh = dir ? Whb : Whf;
    const float* xg = dir ? xgb : xgf;
    float* hout = dir ? hb_out : hf_out;
    float* hbase = hbuf + (size_t)dir * 2 * PARSZ;
    float* cbase = cst + (size_t)dir * PARSZ;

    const int p = dir ? (NW - 1 - s) : s;

    // Per-thread weight row pointers (gate g row = Wh[g*NH+col][ksk..ksk+192)).
    const float4* W0 = (const float4*)(Wh + ((size_t)(0 * NH + col)) * NH + ksk);
    const float4* W1 = (const float4*)(Wh + ((size_t)(1 * NH + col)) * NH + ksk);
    const float4* W2 = (const float4*)(Wh + ((size_t)(2 * NH + col)) * NH + ksk);
    const float4* W3 = (const float4*)(Wh + ((size_t)(3 * NH + col)) * NH + ksk);

    const float* hcur = hbase + (s & 1) * PARSZ;
    // h rows for this thread's 4 batches, k-quarter slice ([b][k] layout).
    const float4* h0 = (const float4*)(hcur + (size_t)(lb0 + 0) * NH + ksk);
    const float4* h1 = (const float4*)(hcur + (size_t)(lb0 + 1) * NH + ksk);
    const float4* h2 = (const float4*)(hcur + (size_t)(lb0 + 2) * NH + ksk);
    const float4* h3 = (const float4*)(hcur + (size_t)(lb0 + 3) * NH + ksk);

    float4 accI = {0,0,0,0}, accF = {0,0,0,0}, accG = {0,0,0,0}, accO = {0,0,0,0};
#pragma unroll 4
    for (int u = 0; u < KR / 4; ++u) {
        float4 w0 = W0[u], w1 = W1[u], w2 = W2[u], w3 = W3[u];
        float4 a = h0[u], b = h1[u], c = h2[u], d = h3[u];
        // gate i (w0), batches a..d
        accI.x = fmaf(a.x, w0.x, accI.x); accI.x = fmaf(a.y, w0.y, accI.x);
        accI.x = fmaf(a.z, w0.z, accI.x); accI.x = fmaf(a.w, w0.w, accI.x);
        accI.y = fmaf(b.x, w0.x, accI.y); accI.y = fmaf(b.y, w0.y, accI.y);
        accI.y = fmaf(b.z, w0.z, accI.y); accI.y = fmaf(b.w, w0.w, accI.y);
        accI.z = fmaf(c.x, w0.x, accI.z); accI.z = fmaf(c.y, w0.y, accI.z);
        accI.z = fmaf(c.z, w0.z, accI.z); accI.z = fmaf(c.w, w0.w, accI.z);
        accI.w = fmaf(d.x, w0.x, accI.w); accI.w = fmaf(d.y, w0.y, accI.w);
        accI.w = fmaf(d.z, w0.z, accI.w); accI.w = fmaf(d.w, w0.w, accI.w);
        // gate f (w1)
        accF.x = fmaf(a.x, w1.x, accF.x); accF.x = fmaf(a.y, w1.y, accF.x);
        accF.x = fmaf(a.z, w1.z, accF.x); accF.x = fmaf(a.w, w1.w, accF.x);
        accF.y = fmaf(b.x, w1.x, accF.y); accF.y = fmaf(b.y, w1.y, accF.y);
        accF.y = fmaf(b.z, w1.z, accF.y); accF.y = fmaf(b.w, w1.w, accF.y);
        accF.z = fmaf(c.x, w1.x, accF.z); accF.z = fmaf(c.y, w1.y, accF.z);
        accF.z = fmaf(c.z, w1.z, accF.z); accF.z = fmaf(c.w, w1.w, accF.z);
        accF.w = fmaf(d.x, w1.x, accF.w); accF.w = fmaf(d.y, w1.y, accF.w);
        accF.w = fmaf(d.z, w1.z, accF.w); accF.w = fmaf(d.w, w1.w, accF.w);
        // gate g (w2)
        accG.x = fmaf(a.x, w2.x, accG.x); accG.x = fmaf(a.y, w2.y, accG.x);
        accG.x = fmaf(a.z, w2.z, accG.x); accG.x = fmaf(a.w, w2.w, accG.x);
        accG.y = fmaf(b.x, w2.x, accG.y); accG.y = fmaf(b.y, w2.y, accG.y);
        accG.y = fmaf(b.z, w2.z, accG.y); accG.y = fmaf(b.w, w2.w, accG.y);
        accG.z = fmaf(c.x, w2.x, accG.z); accG.z = fmaf(c.y, w2.y, accG.z);
        accG.z = fmaf(c.z, w2.z, accG.z); accG.z = fmaf(c.w, w2.w, accG.z);
        accG.w = fmaf(d.x, w2.x, accG.w); accG.w = fmaf(d.y, w2.y, accG.w);
        accG.w = fmaf(d.z, w2.z, accG.w); accG.w = fmaf(d.w, w2.w, accG.w);
        // gate o (w3)
        accO.x = fmaf(a.x, w3.x, accO.x); accO.x = fmaf(a.y, w3.y, accO.x);
        accO.x = fmaf(a.z, w3.z, accO.x); accO.x = fmaf(a.w, w3.w, accO.x);
        accO.y = fmaf(b.x, w3.x, accO.y); accO.y = fmaf(b.y, w3.y, accO.y);
        accO.y = fmaf(b.z, w3.z, accO.y); accO.y = fmaf(b.w, w3.w, accO.y);
        accO.z = fmaf(c.x, w3.x, accO.z); accO.z = fmaf(c.y, w3.y, accO.z);
        accO.z = fmaf(c.z, w3.z, accO.z); accO.z = fmaf(c.w, w3.w, accO.z);
        accO.w = fmaf(d.x, w3.x, accO.w); accO.w = fmaf(d.y, w3.y, accO.w);
        accO.w = fmaf(d.z, w3.z, accO.w); accO.w = fmaf(d.w, w3.w, accO.w);
    }

    // Combine the 4 k-quarters: lane bits 3..4 encode ks.
#pragma unroll
    for (int off = 8; off <= 16; off <<= 1) {
        accI.x += __shfl_xor(accI.x, off); accI.y += __shfl_xor(accI.y, off);
        accI.z += __shfl_xor(accI.z, off); accI.w += __shfl_xor(accI.w, off);
        accF.x += __shfl_xor(accF.x, off); accF.y += __shfl_xor(accF.y, off);
        accF.z += __shfl_xor(accF.z, off); accF.w += __shfl_xor(accF.w, off);
        accG.x += __shfl_xor(accG.x, off); accG.y += __shfl_xor(accG.y, off);
        accG.z += __shfl_xor(accG.z, off); accG.w += __shfl_xor(accG.w, off);
        accO.x += __shfl_xor(accO.x, off); accO.y += __shfl_xor(accO.y, off);
        accO.z += __shfl_xor(accO.z, off); accO.w += __shfl_xor(accO.w, off);
    }

    if (ks == 0) {
        // xg gathers: xg[m][4H], m = lb*NW + p (round-0 proven addressing).
        const size_t b0 = ((size_t)(lb0 + 0) * NW + p) * NG4 + col;
        const size_t b1 = ((size_t)(lb0 + 1) * NW + p) * NG4 + col;
        const size_t b2 = ((size_t)(lb0 + 2) * NW + p) * NG4 + col;
        const size_t b3 = ((size_t)(lb0 + 3) * NW + p) * NG4 + col;
        float4 xgi, xgF, xgG, xgO;
        xgi.x = xg[b0];          xgi.y = xg[b1];
        xgi.z = xg[b2];          xgi.w = xg[b3];
        xgF.x = xg[b0 + NH];     xgF.y = xg[b1 + NH];
        xgF.z = xg[b2 + NH];     xgF.w = xg[b3 + NH];
        xgG.x = xg[b0 + 2*NH];   xgG.y = xg[b1 + 2*NH];
        xgG.z = xg[b2 + 2*NH];   xgG.w = xg[b3 + 2*NH];
        xgO.x = xg[b0 + 3*NH];   xgO.y = xg[b1 + 3*NH];
        xgO.z = xg[b2 + 3*NH];   xgO.w = xg[b3 + 3*NH];

        // cell state ([b][k] layout)
        float4 c4;
        c4.x = cbase[(size_t)(lb0 + 0) * NH + col];
        c4.y = cbase[(size_t)(lb0 + 1) * NH + col];
        c4.z = cbase[(size_t)(lb0 + 2) * NH + col];
        c4.w = cbase[(size_t)(lb0 + 3) * NH + col];

        float4 h4;
#define ACT1(JX) { \
        float iG = sigmoidf_(accI.JX + xgi.JX); \
        float fG = sigmoidf_(accF.JX + xgF.JX); \
        float gG = tanhf(accG.JX + xgG.JX); \
        float oG = sigmoidf_(accO.JX + xgO.JX); \
        c4.JX = fG * c4.JX + iG * gG; \
        h4.JX = oG * tanhf(c4.JX); }
        ACT1(x) ACT1(y) ACT1(z) ACT1(w)
#undef ACT1

        cbase[(size_t)(lb0 + 0) * NH + col] = c4.x;
        cbase[(size_t)(lb0 + 1) * NH + col] = c4.y;
        cbase[(size_t)(lb0 + 2) * NH + col] = c4.z;
        cbase[(size_t)(lb0 + 3) * NH + col] = c4.w;

        // next-step h, parity (s+1)&1, layout [b][k]
        float* hnxt = hbase + ((s + 1) & 1) * PARSZ;
        hnxt[(size_t)(lb0 + 0) * NH + col] = h4.x;
        hnxt[(size_t)(lb0 + 1) * NH + col] = h4.y;
        hnxt[(size_t)(lb0 + 2) * NH + col] = h4.z;
        hnxt[(size_t)(lb0 + 3) * NH + col] = h4.w;

        hout[((size_t)(lb0 + 0) * NW + p) * NH + col] = h4.x;
        hout[((size_t)(lb0 + 1) * NW + p) * NH + col] = h4.y;
        hout[((size_t)(lb0 + 2) * NW + p) * NH + col] = h4.z;
        hout[((size_t)(lb0 + 3) * NW + p) * NH + col] = h4.w;
    }
}

// ---------------------------------------------------------------------------
// Kernel 4 (ROUND-0 VERBATIM): head — logits, softmax, argmax.
// ---------------------------------------------------------------------------
__global__ __launch_bounds__(64) void head_kernel(
    const float* __restrict__ hf, const float* __restrict__ hb,
    const float* __restrict__ Wl, const float* __restrict__ bl,
    float* __restrict__ out) {
    const int m = blockIdx.x;      // 0..8159
    const int lane = threadIdx.x;  // 0..63
    float acc[NCLS];
#pragma unroll
    for (int cI = 0; cI < NCLS; ++cI) acc[cI] = 0.0f;

    const float* hfr = hf + (size_t)m * NH;
    const float* hbr = hb + (size_t)m * NH;
    for (int j = lane; j < NH; j += 64) {
        float v1 = hfr[j];
        float v2 = hbr[j];
#pragma unroll
        for (int cI = 0; cI < NCLS; ++cI) {
            acc[cI] = fmaf(v1, Wl[cI * 2 * NH + j], acc[cI]);
            acc[cI] = fmaf(v2, Wl[cI * 2 * NH + NH + j], acc[cI]);
        }
    }
#pragma unroll
    for (int cI = 0; cI < NCLS; ++cI)
        for (int off = 32; off > 0; off >>= 1)
            acc[cI] += __shfl_down(acc[cI], off);

    if (lane == 0) {
        float logit[NCLS];
        float mx = -1e30f;
#pragma unroll
        for (int cI = 0; cI < NCLS; ++cI) {
            logit[cI] = acc[cI] + bl[cI];
            mx = fmaxf(mx, logit[cI]);
        }
        float e[NCLS];
        float sum = 0.0f;
#pragma unroll
        for (int cI = 0; cI < NCLS; ++cI) { e[cI] = expf(logit[cI] - mx); sum += e[cI]; }
        float inv = 1.0f / sum;
        int best = 0;
        float bestv = -1.0f;
#pragma unroll
        for (int cI = 0; cI < NCLS; ++cI) {
            float p = e[cI] * inv;
            out[(size_t)m * NCLS + cI] = p;
            if (p > bestv) { bestv = p; best = cI; }  // first-occurrence argmax
        }
        out[(size_t)NMTOT * NCLS + m] = (float)best;
    }
}

// ---------------------------------------------------------------------------
extern "C" void kernel_launch(void* const* d_in, const int* in_sizes, int n_in,
                              void* d_out, int out_size, void* d_ws, size_t ws_size,
                              hipStream_t stream) {
    const float* bert     = (const float*)d_in[0];
    const int*   word_ids = (const int*)d_in[1];
    const float* W_ih_f   = (const float*)d_in[2];
    const float* W_hh_f   = (const float*)d_in[3];
    const float* b_f      = (const float*)d_in[4];
    const float* W_ih_b   = (const float*)d_in[5];
    const float* W_hh_b   = (const float*)d_in[6];
    const float* b_b      = (const float*)d_in[7];
    const float* W_lin    = (const float*)d_in[8];
    const float* b_lin    = (const float*)d_in[9];
    float* out = (float*)d_out;   // f32: prob [8160*9] then path [8160]

    char* ws = (char*)d_ws;
    size_t off = 0;
    auto alloc = [&](size_t bytes) -> void* {
        void* p = ws + off;
        off += (bytes + 255) & ~(size_t)255;
        return p;
    };
    int*   rowbase = (int*)alloc((size_t)NMTOT * sizeof(int));
    float* xgf = (float*)alloc((size_t)NMTOT * NG4 * sizeof(float));   // 100 MB
    float* xgb = (float*)alloc((size_t)NMTOT * NG4 * sizeof(float));   // 100 MB
    float* hf  = (float*)alloc((size_t)NMTOT * NH * sizeof(float));    // 25 MB
    float* hb  = (float*)alloc((size_t)NMTOT * NH * sizeof(float));    // 25 MB
    float* hbuf = (float*)alloc((size_t)4 * PARSZ * sizeof(float));    // 384 KB
    float* cst  = (float*)alloc((size_t)2 * PARSZ * sizeof(float));    // 192 KB

    pool_idx_kernel<<<NB, 256, 0, stream>>>(word_ids, rowbase);

    dim3 ggrid(NG4 / 128, (NMTOT + 127) / 128, 2);
    gemm_xg_kernel<<<ggrid, 256, 0, stream>>>(bert, rowbase, W_ih_f, b_f,
                                              W_ih_b, b_b, xgf, xgb);

    // Zero recurrence state (ws is poisoned before every call).
    hipMemsetAsync(hbuf, 0, (size_t)4 * PARSZ * sizeof(float), stream);
    hipMemsetAsync(cst,  0, (size_t)2 * PARSZ * sizeof(float), stream);

    // 255 sequential per-step launches: kernel boundary = grid-wide barrier.
    for (int s = 0; s < NW; ++s) {
        lstm_step_kernel<<<dim3(256), dim3(192), 0, stream>>>(
            s, xgf, xgb, W_hh_f, W_hh_b, hf, hb, hbuf, cst);
    }

    head_kernel<<<NMTOT, 64, 0, stream>>>(hf, hb, W_lin, b_lin, out);
}

// Round 14
// 5994.424 us; speedup vs baseline: 3.3412x; 1.8012x over previous
//
#include <hip/hip_runtime.h>
#include <hip/hip_bf16.h>

// Problem constants
constexpr int NB   = 32;    // batch
constexpr int NT   = 512;   // tokens
constexpr int ND   = 768;   // bert dim
constexpr int NW   = 255;   // words
constexpr int NH   = 768;   // lstm hidden
constexpr int NCLS = 9;     // NER classes
constexpr int NMTOT = NB * NW;          // 8160 rows
constexpr int NG4  = 4 * NH;            // 3072 gate dim
constexpr int PARSZ = NH * NB;          // 24576 floats per h parity buffer
constexpr int KR   = NH / 4;            // 192 k per k-quarter
constexpr int LROW = 772;               // padded LDS row stride (f32)

__device__ __forceinline__ float sigmoidf_(float x) {
    return 1.0f / (1.0f + expf(-x));
}

// ---------------------------------------------------------------------------
// Kernel 1 (VERBATIM, proven): first-subword index per (b, w).
// ---------------------------------------------------------------------------
__global__ void pool_idx_kernel(const int* __restrict__ word_ids,
                                int* __restrict__ rowbase) {
    int bb = blockIdx.x;
    int w = threadIdx.x;
    if (w >= NW) return;
    const int* row = word_ids + bb * NT;
    int ft = 0;
    for (int t = 0; t < NT; ++t) {
        if (row[t] == w) { ft = t; break; }
    }
    rowbase[bb * NW + w] = (bb * NT + ft) * ND;
}

// ---------------------------------------------------------------------------
// Kernel 2 (VERBATIM, proven): xg[dir] = pooled @ W_ih[dir]^T + b[dir] (f32)
// Row-major output xg[m][4H], m = b*NW + w.
// ---------------------------------------------------------------------------
__global__ __launch_bounds__(256) void gemm_xg_kernel(
    const float* __restrict__ bert, const int* __restrict__ rowbase,
    const float* __restrict__ Wf, const float* __restrict__ biasf,
    const float* __restrict__ Wb, const float* __restrict__ biasb,
    float* __restrict__ xgf, float* __restrict__ xgb) {
    const int dir = blockIdx.z;
    const float* Wt = dir ? Wb : Wf;
    const float* bias = dir ? biasb : biasf;
    float* xg = dir ? xgb : xgf;
    const int m0 = blockIdx.y * 128;
    const int n0 = blockIdx.x * 128;

    __shared__ float As[8][128];
    __shared__ float Bs[8][128];

    const int t = threadIdx.x;
    const int lrow = t >> 1;        // 0..127
    const int lk = (t & 1) * 4;     // 0 or 4

    int am = m0 + lrow;
    const float* aptr = bert + (am < NMTOT ? rowbase[am] : rowbase[NMTOT - 1]) + lk;
    const float* bptr = Wt + (size_t)(n0 + lrow) * ND + lk;

    const int tm = (t & 15) * 8;
    const int tn = (t >> 4) * 8;

    float acc[8][8] = {};

    for (int k0 = 0; k0 < ND; k0 += 8) {
        float4 av = *(const float4*)(aptr + k0);
        float4 bv = *(const float4*)(bptr + k0);
        __syncthreads();
        As[lk + 0][lrow] = av.x; As[lk + 1][lrow] = av.y;
        As[lk + 2][lrow] = av.z; As[lk + 3][lrow] = av.w;
        Bs[lk + 0][lrow] = bv.x; Bs[lk + 1][lrow] = bv.y;
        Bs[lk + 2][lrow] = bv.z; Bs[lk + 3][lrow] = bv.w;
        __syncthreads();
#pragma unroll
        for (int kk = 0; kk < 8; ++kk) {
            float ar[8], br[8];
#pragma unroll
            for (int i = 0; i < 8; ++i) ar[i] = As[kk][tm + i];
#pragma unroll
            for (int j = 0; j < 8; ++j) br[j] = Bs[kk][tn + j];
#pragma unroll
            for (int i = 0; i < 8; ++i)
#pragma unroll
                for (int j = 0; j < 8; ++j)
                    acc[i][j] = fmaf(ar[i], br[j], acc[i][j]);
        }
    }

#pragma unroll
    for (int i = 0; i < 8; ++i) {
        int m = m0 + tm + i;
        if (m >= NMTOT) continue;
        float* orow = xg + (size_t)m * NG4 + n0 + tn;
#pragma unroll
        for (int j = 0; j < 8; ++j) orow[j] = acc[i][j] + bias[n0 + tn + j];
    }
}

// ---------------------------------------------------------------------------
// Kernel 3: ONE LSTM time step (sequential launches, proven frame) — now with
// LDS-staged h and full-SIMD occupancy.
// 256 blocks x 384 threads, 49408 B dynamic LDS.
// Block: dir = blk>>7; r = blk&127; cg = r>>1 (12-col group), bh = r&1
// (batch half: batches bh*16..+15). Thread t: ci = t>>5 (0..11, col),
// ks = (t>>3)&3 (k quarter, bits 3..4 — same as the PASSING R11 layout),
// lbq = t&7 (batch pair -> local batches lbq*2, lbq*2+1).
// Stage: h[16 local batches][768] from hbuf -> LDS [16][LROW=772] (padded:
// batch-pair lanes spread across bank groups; same-address ks/ci lanes
// broadcast; worst 2-way conflict = free).
// Dot: per thread 2 batches x 192 k x 4 gates from LDS(h) + L2(weights,
// shared rows broadcast within the wave). Combine ks via __shfl_xor(8/16).
// ks==0 lanes: xg + c loads, activations, h/hout/c stores (2 batches each).
// ---------------------------------------------------------------------------
__global__ __launch_bounds__(384) void lstm_step_kernel(
    const int s,
    const float* __restrict__ xgf, const float* __restrict__ xgb,
    const float* __restrict__ Whf, const float* __restrict__ Whb,
    float* __restrict__ hf_out, float* __restrict__ hb_out,
    float* __restrict__ hbuf /* [2 dir][2 par][PARSZ] */,
    float* __restrict__ cst  /* [2 dir][PARSZ] */) {
    extern __shared__ float hl[];     // [16][LROW]

    const int blk = blockIdx.x;       // 0..255
    const int dir = blk >> 7;
    const int r = blk & 127;
    const int cg = r >> 1;            // 0..63
    const int bh = r & 1;             // batch half
    const int t = threadIdx.x;        // 0..383
    const int ci = t >> 5;            // 0..11 local col
    const int ks = (t >> 3) & 3;      // 0..3 k quarter
    const int lbq = t & 7;            // 0..7 batch pair
    const int col = cg * 12 + ci;
    const int lb0 = lbq * 2;          // local batch base (0..14)
    const int bbase = bh * 16;        // global batch base
    const int ksk = ks * KR;          // k-quarter base

    const float* Wh = dir ? Whb : Whf;
    const float* xg = dir ? xgb : xgf;
    float* hout = dir ? hb_out : hf_out;
    float* hbase = hbuf + (size_t)dir * 2 * PARSZ;
    float* cbase = cst + (size_t)dir * PARSZ;

    const int p = dir ? (NW - 1 - s) : s;

    // ---- Stage h[bbase..bbase+15][0..767] -> LDS [16][LROW]
    {
        const float* hcur = hbase + (s & 1) * PARSZ;
        for (int idx = t; idx < 16 * 192; idx += 384) {
            const int b = idx / 192;
            const int kq = idx - b * 192;         // float4 index in k
            float4 v = *(const float4*)(hcur + (size_t)(bbase + b) * NH + kq * 4);
            *(float4*)(hl + (size_t)b * LROW + kq * 4) = v;
        }
    }
    __syncthreads();

    // Per-thread weight row pointers (gate g row = Wh[g*NH+col][ksk..+192)).
    const float4* W0 = (const float4*)(Wh + ((size_t)(0 * NH + col)) * NH + ksk);
    const float4* W1 = (const float4*)(Wh + ((size_t)(1 * NH + col)) * NH + ksk);
    const float4* W2 = (const float4*)(Wh + ((size_t)(2 * NH + col)) * NH + ksk);
    const float4* W3 = (const float4*)(Wh + ((size_t)(3 * NH + col)) * NH + ksk);

    // LDS h rows for this thread's 2 batches, k-quarter slice.
    const float4* h0 = (const float4*)(hl + (size_t)(lb0 + 0) * LROW + ksk);
    const float4* h1 = (const float4*)(hl + (size_t)(lb0 + 1) * LROW + ksk);

    float2 accI = {0,0}, accF = {0,0}, accG = {0,0}, accO = {0,0};
#pragma unroll 4
    for (int u = 0; u < KR / 4; ++u) {
        float4 w0 = W0[u], w1 = W1[u], w2 = W2[u], w3 = W3[u];
        float4 a = h0[u], b = h1[u];
        // gate i
        accI.x = fmaf(a.x, w0.x, accI.x); accI.x = fmaf(a.y, w0.y, accI.x);
        accI.x = fmaf(a.z, w0.z, accI.x); accI.x = fmaf(a.w, w0.w, accI.x);
        accI.y = fmaf(b.x, w0.x, accI.y); accI.y = fmaf(b.y, w0.y, accI.y);
        accI.y = fmaf(b.z, w0.z, accI.y); accI.y = fmaf(b.w, w0.w, accI.y);
        // gate f
        accF.x = fmaf(a.x, w1.x, accF.x); accF.x = fmaf(a.y, w1.y, accF.x);
        accF.x = fmaf(a.z, w1.z, accF.x); accF.x = fmaf(a.w, w1.w, accF.x);
        accF.y = fmaf(b.x, w1.x, accF.y); accF.y = fmaf(b.y, w1.y, accF.y);
        accF.y = fmaf(b.z, w1.z, accF.y); accF.y = fmaf(b.w, w1.w, accF.y);
        // gate g
        accG.x = fmaf(a.x, w2.x, accG.x); accG.x = fmaf(a.y, w2.y, accG.x);
        accG.x = fmaf(a.z, w2.z, accG.x); accG.x = fmaf(a.w, w2.w, accG.x);
        accG.y = fmaf(b.x, w2.x, accG.y); accG.y = fmaf(b.y, w2.y, accG.y);
        accG.y = fmaf(b.z, w2.z, accG.y); accG.y = fmaf(b.w, w2.w, accG.y);
        // gate o
        accO.x = fmaf(a.x, w3.x, accO.x); accO.x = fmaf(a.y, w3.y, accO.x);
        accO.x = fmaf(a.z, w3.z, accO.x); accO.x = fmaf(a.w, w3.w, accO.x);
        accO.y = fmaf(b.x, w3.x, accO.y); accO.y = fmaf(b.y, w3.y, accO.y);
        accO.y = fmaf(b.z, w3.z, accO.y); accO.y = fmaf(b.w, w3.w, accO.y);
    }

    // Combine the 4 k-quarters: lane bits 3..4 encode ks (same as R11).
#pragma unroll
    for (int off = 8; off <= 16; off <<= 1) {
        accI.x += __shfl_xor(accI.x, off); accI.y += __shfl_xor(accI.y, off);
        accF.x += __shfl_xor(accF.x, off); accF.y += __shfl_xor(accF.y, off);
        accG.x += __shfl_xor(accG.x, off); accG.y += __shfl_xor(accG.y, off);
        accO.x += __shfl_xor(accO.x, off); accO.y += __shfl_xor(accO.y, off);
    }

    if (ks == 0) {
        const int b0g = bbase + lb0;          // global batch of .x
        const int b1g = b0g + 1;              // global batch of .y
        // xg gathers: xg[m][4H], m = b*NW + p (R11-proven addressing).
        const size_t a0 = ((size_t)b0g * NW + p) * NG4 + col;
        const size_t a1 = ((size_t)b1g * NW + p) * NG4 + col;
        float2 xgi, xgF, xgG, xgO;
        xgi.x = xg[a0];          xgi.y = xg[a1];
        xgF.x = xg[a0 + NH];     xgF.y = xg[a1 + NH];
        xgG.x = xg[a0 + 2*NH];   xgG.y = xg[a1 + 2*NH];
        xgO.x = xg[a0 + 3*NH];   xgO.y = xg[a1 + 3*NH];

        float2 c2;
        c2.x = cbase[(size_t)b0g * NH + col];
        c2.y = cbase[(size_t)b1g * NH + col];

        float2 h2;
#define ACT1(JX) { \
        float iG = sigmoidf_(accI.JX + xgi.JX); \
        float fG = sigmoidf_(accF.JX + xgF.JX); \
        float gG = tanhf(accG.JX + xgG.JX); \
        float oG = sigmoidf_(accO.JX + xgO.JX); \
        c2.JX = fG * c2.JX + iG * gG; \
        h2.JX = oG * tanhf(c2.JX); }
        ACT1(x) ACT1(y)
#undef ACT1

        cbase[(size_t)b0g * NH + col] = c2.x;
        cbase[(size_t)b1g * NH + col] = c2.y;

        float* hnxt = hbase + ((s + 1) & 1) * PARSZ;
        hnxt[(size_t)b0g * NH + col] = h2.x;
        hnxt[(size_t)b1g * NH + col] = h2.y;

        hout[((size_t)b0g * NW + p) * NH + col] = h2.x;
        hout[((size_t)b1g * NW + p) * NH + col] = h2.y;
    }
}

// ---------------------------------------------------------------------------
// Kernel 4 (VERBATIM, proven): head — logits, softmax, argmax.
// ---------------------------------------------------------------------------
__global__ __launch_bounds__(64) void head_kernel(
    const float* __restrict__ hf, const float* __restrict__ hb,
    const float* __restrict__ Wl, const float* __restrict__ bl,
    float* __restrict__ out) {
    const int m = blockIdx.x;      // 0..8159
    const int lane = threadIdx.x;  // 0..63
    float acc[NCLS];
#pragma unroll
    for (int cI = 0; cI < NCLS; ++cI) acc[cI] = 0.0f;

    const float* hfr = hf + (size_t)m * NH;
    const float* hbr = hb + (size_t)m * NH;
    for (int j = lane; j < NH; j += 64) {
        float v1 = hfr[j];
        float v2 = hbr[j];
#pragma unroll
        for (int cI = 0; cI < NCLS; ++cI) {
            acc[cI] = fmaf(v1, Wl[cI * 2 * NH + j], acc[cI]);
            acc[cI] = fmaf(v2, Wl[cI * 2 * NH + NH + j], acc[cI]);
        }
    }
#pragma unroll
    for (int cI = 0; cI < NCLS; ++cI)
        for (int off = 32; off > 0; off >>= 1)
            acc[cI] += __shfl_down(acc[cI], off);

    if (lane == 0) {
        float logit[NCLS];
        float mx = -1e30f;
#pragma unroll
        for (int cI = 0; cI < NCLS; ++cI) {
            logit[cI] = acc[cI] + bl[cI];
            mx = fmaxf(mx, logit[cI]);
        }
        float e[NCLS];
        float sum = 0.0f;
#pragma unroll
        for (int cI = 0; cI < NCLS; ++cI) { e[cI] = expf(logit[cI] - mx); sum += e[cI]; }
        float inv = 1.0f / sum;
        int best = 0;
        float bestv = -1.0f;
#pragma unroll
        for (int cI = 0; cI < NCLS; ++cI) {
            float p = e[cI] * inv;
            out[(size_t)m * NCLS + cI] = p;
            if (p > bestv) { bestv = p; best = cI; }  // first-occurrence argmax
        }
        out[(size_t)NMTOT * NCLS + m] = (float)best;
    }
}

// ---------------------------------------------------------------------------
extern "C" void kernel_launch(void* const* d_in, const int* in_sizes, int n_in,
                              void* d_out, int out_size, void* d_ws, size_t ws_size,
                              hipStream_t stream) {
    const float* bert     = (const float*)d_in[0];
    const int*   word_ids = (const int*)d_in[1];
    const float* W_ih_f   = (const float*)d_in[2];
    const float* W_hh_f   = (const float*)d_in[3];
    const float* b_f      = (const float*)d_in[4];
    const float* W_ih_b   = (const float*)d_in[5];
    const float* W_hh_b   = (const float*)d_in[6];
    const float* b_b      = (const float*)d_in[7];
    const float* W_lin    = (const float*)d_in[8];
    const float* b_lin    = (const float*)d_in[9];
    float* out = (float*)d_out;   // f32: prob [8160*9] then path [8160]

    char* ws = (char*)d_ws;
    size_t off = 0;
    auto alloc = [&](size_t bytes) -> void* {
        void* p = ws + off;
        off += (bytes + 255) & ~(size_t)255;
        return p;
    };
    int*   rowbase = (int*)alloc((size_t)NMTOT * sizeof(int));
    float* xgf = (float*)alloc((size_t)NMTOT * NG4 * sizeof(float));   // 100 MB
    float* xgb = (float*)alloc((size_t)NMTOT * NG4 * sizeof(float));   // 100 MB
    float* hf  = (float*)alloc((size_t)NMTOT * NH * sizeof(float));    // 25 MB
    float* hb  = (float*)alloc((size_t)NMTOT * NH * sizeof(float));    // 25 MB
    float* hbuf = (float*)alloc((size_t)4 * PARSZ * sizeof(float));    // 384 KB
    float* cst  = (float*)alloc((size_t)2 * PARSZ * sizeof(float));    // 192 KB

    pool_idx_kernel<<<NB, 256, 0, stream>>>(word_ids, rowbase);

    dim3 ggrid(NG4 / 128, (NMTOT + 127) / 128, 2);
    gemm_xg_kernel<<<ggrid, 256, 0, stream>>>(bert, rowbase, W_ih_f, b_f,
                                              W_ih_b, b_b, xgf, xgb);

    // Zero recurrence state (ws is poisoned before every call).
    hipMemsetAsync(hbuf, 0, (size_t)4 * PARSZ * sizeof(float), stream);
    hipMemsetAsync(cst,  0, (size_t)2 * PARSZ * sizeof(float), stream);

    // 255 sequential per-step launches: kernel boundary = grid-wide barrier.
    const size_t lds_bytes = (size_t)16 * LROW * sizeof(float);  // 49408 B
    for (int s = 0; s < NW; ++s) {
        lstm_step_kernel<<<dim3(256), dim3(384), lds_bytes, stream>>>(
            s, xgf, xgb, W_hh_f, W_hh_b, hf, hb, hbuf, cst);
    }

    head_kernel<<<NMTOT, 64, 0, stream>>>(hf, hb, W_lin, b_lin, out);
}

// Round 15
// 5437.679 us; speedup vs baseline: 3.6833x; 1.1024x over previous
//
#include <hip/hip_runtime.h>
#include <hip/hip_bf16.h>

// Problem constants
constexpr int NB   = 32;    // batch
constexpr int NT   = 512;   // tokens
constexpr int ND   = 768;   // bert dim
constexpr int NW   = 255;   // words
constexpr int NH   = 768;   // lstm hidden
constexpr int NCLS = 9;     // NER classes
constexpr int NMTOT = NB * NW;          // 8160 rows
constexpr int NG4  = 4 * NH;            // 3072 gate dim
constexpr int PARSZ = NH * NB;          // 24576 floats per h parity buffer
constexpr int KR   = NH / 4;            // 192 k per k-quarter
constexpr int LROW = 772;               // padded LDS row stride (f32)

__device__ __forceinline__ float sigmoidf_(float x) {
    return 1.0f / (1.0f + expf(-x));
}

// ---------------------------------------------------------------------------
// Kernel 1 (VERBATIM, proven): first-subword index per (b, w).
// ---------------------------------------------------------------------------
__global__ void pool_idx_kernel(const int* __restrict__ word_ids,
                                int* __restrict__ rowbase) {
    int bb = blockIdx.x;
    int w = threadIdx.x;
    if (w >= NW) return;
    const int* row = word_ids + bb * NT;
    int ft = 0;
    for (int t = 0; t < NT; ++t) {
        if (row[t] == w) { ft = t; break; }
    }
    rowbase[bb * NW + w] = (bb * NT + ft) * ND;
}

// ---------------------------------------------------------------------------
// Kernel 2 (VERBATIM, proven): xg[dir] = pooled @ W_ih[dir]^T + b[dir] (f32)
// Row-major output xg[m][4H], m = b*NW + w.
// ---------------------------------------------------------------------------
__global__ __launch_bounds__(256) void gemm_xg_kernel(
    const float* __restrict__ bert, const int* __restrict__ rowbase,
    const float* __restrict__ Wf, const float* __restrict__ biasf,
    const float* __restrict__ Wb, const float* __restrict__ biasb,
    float* __restrict__ xgf, float* __restrict__ xgb) {
    const int dir = blockIdx.z;
    const float* Wt = dir ? Wb : Wf;
    const float* bias = dir ? biasb : biasf;
    float* xg = dir ? xgb : xgf;
    const int m0 = blockIdx.y * 128;
    const int n0 = blockIdx.x * 128;

    __shared__ float As[8][128];
    __shared__ float Bs[8][128];

    const int t = threadIdx.x;
    const int lrow = t >> 1;        // 0..127
    const int lk = (t & 1) * 4;     // 0 or 4

    int am = m0 + lrow;
    const float* aptr = bert + (am < NMTOT ? rowbase[am] : rowbase[NMTOT - 1]) + lk;
    const float* bptr = Wt + (size_t)(n0 + lrow) * ND + lk;

    const int tm = (t & 15) * 8;
    const int tn = (t >> 4) * 8;

    float acc[8][8] = {};

    for (int k0 = 0; k0 < ND; k0 += 8) {
        float4 av = *(const float4*)(aptr + k0);
        float4 bv = *(const float4*)(bptr + k0);
        __syncthreads();
        As[lk + 0][lrow] = av.x; As[lk + 1][lrow] = av.y;
        As[lk + 2][lrow] = av.z; As[lk + 3][lrow] = av.w;
        Bs[lk + 0][lrow] = bv.x; Bs[lk + 1][lrow] = bv.y;
        Bs[lk + 2][lrow] = bv.z; Bs[lk + 3][lrow] = bv.w;
        __syncthreads();
#pragma unroll
        for (int kk = 0; kk < 8; ++kk) {
            float ar[8], br[8];
#pragma unroll
            for (int i = 0; i < 8; ++i) ar[i] = As[kk][tm + i];
#pragma unroll
            for (int j = 0; j < 8; ++j) br[j] = Bs[kk][tn + j];
#pragma unroll
            for (int i = 0; i < 8; ++i)
#pragma unroll
                for (int j = 0; j < 8; ++j)
                    acc[i][j] = fmaf(ar[i], br[j], acc[i][j]);
        }
    }

#pragma unroll
    for (int i = 0; i < 8; ++i) {
        int m = m0 + tm + i;
        if (m >= NMTOT) continue;
        float* orow = xg + (size_t)m * NG4 + n0 + tn;
#pragma unroll
        for (int j = 0; j < 8; ++j) orow[j] = acc[i][j] + bias[n0 + tn + j];
    }
}

// ---------------------------------------------------------------------------
// Kernel 3: ONE LSTM time step (sequential launches, proven frame).
// R14 text + ONE change: XCD-aware block remap for weight L2 residency.
// 256 blocks x 384 threads, 49408 B dynamic LDS.
// Remap: xcd = blk&7 (dispatch round-robin), ii = blk>>3; bh = ii&1,
// (dir,cg) = ((ii>>1)<<3)|xcd. Both bh-halves of one (dir,cg) — which read
// the SAME 147 KB weight slice — land on the SAME XCD: per-XCD footprint
// 16 slices x 147 KB = 2.36 MB < 4 MB L2 (was 32 x 147 KB = 4.6 MB, which
// sweeps past the 4 MB LRU every step -> ~37 MB/step HBM re-fetch).
// Thread t: ci = t>>5 (0..11, col), ks = (t>>3)&3 (k quarter, bits 3..4 —
// PASSING R11/R14 layout), lbq = t&7 (batch pair).
// Stage: h[16 local batches][768] -> LDS [16][LROW=772] (padded).
// Dot: per thread 2 batches x 192 k x 4 gates from LDS(h) + L2(weights).
// Combine ks via __shfl_xor(8/16); ks==0 lanes: xg+c, activations, stores.
// ---------------------------------------------------------------------------
__global__ __launch_bounds__(384) void lstm_step_kernel(
    const int s,
    const float* __restrict__ xgf, const float* __restrict__ xgb,
    const float* __restrict__ Whf, const float* __restrict__ Whb,
    float* __restrict__ hf_out, float* __restrict__ hb_out,
    float* __restrict__ hbuf /* [2 dir][2 par][PARSZ] */,
    float* __restrict__ cst  /* [2 dir][PARSZ] */) {
    extern __shared__ float hl[];     // [16][LROW]

    const int blk = blockIdx.x;       // 0..255
    // XCD-aware remap (bijective: (xcd, ii) <-> (dir, cg, bh)).
    const int xcd = blk & 7;
    const int ii  = blk >> 3;         // 0..31
    const int bh  = ii & 1;           // batch half
    const int idx = ((ii >> 1) << 3) | xcd;   // 0..127 distinct (dir,cg)
    const int dir = idx >> 6;
    const int cg  = idx & 63;

    const int t = threadIdx.x;        // 0..383
    const int ci = t >> 5;            // 0..11 local col
    const int ks = (t >> 3) & 3;      // 0..3 k quarter
    const int lbq = t & 7;            // 0..7 batch pair
    const int col = cg * 12 + ci;
    const int lb0 = lbq * 2;          // local batch base (0..14)
    const int bbase = bh * 16;        // global batch base
    const int ksk = ks * KR;          // k-quarter base

    const float* Wh = dir ? Whb : Whf;
    const float* xg = dir ? xgb : xgf;
    float* hout = dir ? hb_out : hf_out;
    float* hbase = hbuf + (size_t)dir * 2 * PARSZ;
    float* cbase = cst + (size_t)dir * PARSZ;

    const int p = dir ? (NW - 1 - s) : s;

    // ---- Stage h[bbase..bbase+15][0..767] -> LDS [16][LROW]
    {
        const float* hcur = hbase + (s & 1) * PARSZ;
        for (int idx2 = t; idx2 < 16 * 192; idx2 += 384) {
            const int b = idx2 / 192;
            const int kq = idx2 - b * 192;        // float4 index in k
            float4 v = *(const float4*)(hcur + (size_t)(bbase + b) * NH + kq * 4);
            *(float4*)(hl + (size_t)b * LROW + kq * 4) = v;
        }
    }
    __syncthreads();

    // Per-thread weight row pointers (gate g row = Wh[g*NH+col][ksk..+192)).
    const float4* W0 = (const float4*)(Wh + ((size_t)(0 * NH + col)) * NH + ksk);
    const float4* W1 = (const float4*)(Wh + ((size_t)(1 * NH + col)) * NH + ksk);
    const float4* W2 = (const float4*)(Wh + ((size_t)(2 * NH + col)) * NH + ksk);
    const float4* W3 = (const float4*)(Wh + ((size_t)(3 * NH + col)) * NH + ksk);

    // LDS h rows for this thread's 2 batches, k-quarter slice.
    const float4* h0 = (const float4*)(hl + (size_t)(lb0 + 0) * LROW + ksk);
    const float4* h1 = (const float4*)(hl + (size_t)(lb0 + 1) * LROW + ksk);

    float2 accI = {0,0}, accF = {0,0}, accG = {0,0}, accO = {0,0};
#pragma unroll 4
    for (int u = 0; u < KR / 4; ++u) {
        float4 w0 = W0[u], w1 = W1[u], w2 = W2[u], w3 = W3[u];
        float4 a = h0[u], b = h1[u];
        // gate i
        accI.x = fmaf(a.x, w0.x, accI.x); accI.x = fmaf(a.y, w0.y, accI.x);
        accI.x = fmaf(a.z, w0.z, accI.x); accI.x = fmaf(a.w, w0.w, accI.x);
        accI.y = fmaf(b.x, w0.x, accI.y); accI.y = fmaf(b.y, w0.y, accI.y);
        accI.y = fmaf(b.z, w0.z, accI.y); accI.y = fmaf(b.w, w0.w, accI.y);
        // gate f
        accF.x = fmaf(a.x, w1.x, accF.x); accF.x = fmaf(a.y, w1.y, accF.x);
        accF.x = fmaf(a.z, w1.z, accF.x); accF.x = fmaf(a.w, w1.w, accF.x);
        accF.y = fmaf(b.x, w1.x, accF.y); accF.y = fmaf(b.y, w1.y, accF.y);
        accF.y = fmaf(b.z, w1.z, accF.y); accF.y = fmaf(b.w, w1.w, accF.y);
        // gate g
        accG.x = fmaf(a.x, w2.x, accG.x); accG.x = fmaf(a.y, w2.y, accG.x);
        accG.x = fmaf(a.z, w2.z, accG.x); accG.x = fmaf(a.w, w2.w, accG.x);
        accG.y = fmaf(b.x, w2.x, accG.y); accG.y = fmaf(b.y, w2.y, accG.y);
        accG.y = fmaf(b.z, w2.z, accG.y); accG.y = fmaf(b.w, w2.w, accG.y);
        // gate o
        accO.x = fmaf(a.x, w3.x, accO.x); accO.x = fmaf(a.y, w3.y, accO.x);
        accO.x = fmaf(a.z, w3.z, accO.x); accO.x = fmaf(a.w, w3.w, accO.x);
        accO.y = fmaf(b.x, w3.x, accO.y); accO.y = fmaf(b.y, w3.y, accO.y);
        accO.y = fmaf(b.z, w3.z, accO.y); accO.y = fmaf(b.w, w3.w, accO.y);
    }

    // Combine the 4 k-quarters: lane bits 3..4 encode ks (same as R11/R14).
#pragma unroll
    for (int off = 8; off <= 16; off <<= 1) {
        accI.x += __shfl_xor(accI.x, off); accI.y += __shfl_xor(accI.y, off);
        accF.x += __shfl_xor(accF.x, off); accF.y += __shfl_xor(accF.y, off);
        accG.x += __shfl_xor(accG.x, off); accG.y += __shfl_xor(accG.y, off);
        accO.x += __shfl_xor(accO.x, off); accO.y += __shfl_xor(accO.y, off);
    }

    if (ks == 0) {
        const int b0g = bbase + lb0;          // global batch of .x
        const int b1g = b0g + 1;              // global batch of .y
        // xg gathers: xg[m][4H], m = b*NW + p (R11-proven addressing).
        const size_t a0 = ((size_t)b0g * NW + p) * NG4 + col;
        const size_t a1 = ((size_t)b1g * NW + p) * NG4 + col;
        float2 xgi, xgF, xgG, xgO;
        xgi.x = xg[a0];          xgi.y = xg[a1];
        xgF.x = xg[a0 + NH];     xgF.y = xg[a1 + NH];
        xgG.x = xg[a0 + 2*NH];   xgG.y = xg[a1 + 2*NH];
        xgO.x = xg[a0 + 3*NH];   xgO.y = xg[a1 + 3*NH];

        float2 c2;
        c2.x = cbase[(size_t)b0g * NH + col];
        c2.y = cbase[(size_t)b1g * NH + col];

        float2 h2;
#define ACT1(JX) { \
        float iG = sigmoidf_(accI.JX + xgi.JX); \
        float fG = sigmoidf_(accF.JX + xgF.JX); \
        float gG = tanhf(accG.JX + xgG.JX); \
        float oG = sigmoidf_(accO.JX + xgO.JX); \
        c2.JX = fG * c2.JX + iG * gG; \
        h2.JX = oG * tanhf(c2.JX); }
        ACT1(x) ACT1(y)
#undef ACT1

        cbase[(size_t)b0g * NH + col] = c2.x;
        cbase[(size_t)b1g * NH + col] = c2.y;

        float* hnxt = hbase + ((s + 1) & 1) * PARSZ;
        hnxt[(size_t)b0g * NH + col] = h2.x;
        hnxt[(size_t)b1g * NH + col] = h2.y;

        hout[((size_t)b0g * NW + p) * NH + col] = h2.x;
        hout[((size_t)b1g * NW + p) * NH + col] = h2.y;
    }
}

// ---------------------------------------------------------------------------
// Kernel 4 (VERBATIM, proven): head — logits, softmax, argmax.
// ---------------------------------------------------------------------------
__global__ __launch_bounds__(64) void head_kernel(
    const float* __restrict__ hf, const float* __restrict__ hb,
    const float* __restrict__ Wl, const float* __restrict__ bl,
    float* __restrict__ out) {
    const int m = blockIdx.x;      // 0..8159
    const int lane = threadIdx.x;  // 0..63
    float acc[NCLS];
#pragma unroll
    for (int cI = 0; cI < NCLS; ++cI) acc[cI] = 0.0f;

    const float* hfr = hf + (size_t)m * NH;
    const float* hbr = hb + (size_t)m * NH;
    for (int j = lane; j < NH; j += 64) {
        float v1 = hfr[j];
        float v2 = hbr[j];
#pragma unroll
        for (int cI = 0; cI < NCLS; ++cI) {
            acc[cI] = fmaf(v1, Wl[cI * 2 * NH + j], acc[cI]);
            acc[cI] = fmaf(v2, Wl[cI * 2 * NH + NH + j], acc[cI]);
        }
    }
#pragma unroll
    for (int cI = 0; cI < NCLS; ++cI)
        for (int off = 32; off > 0; off >>= 1)
            acc[cI] += __shfl_down(acc[cI], off);

    if (lane == 0) {
        float logit[NCLS];
        float mx = -1e30f;
#pragma unroll
        for (int cI = 0; cI < NCLS; ++cI) {
            logit[cI] = acc[cI] + bl[cI];
            mx = fmaxf(mx, logit[cI]);
        }
        float e[NCLS];
        float sum = 0.0f;
#pragma unroll
        for (int cI = 0; cI < NCLS; ++cI) { e[cI] = expf(logit[cI] - mx); sum += e[cI]; }
        float inv = 1.0f / sum;
        int best = 0;
        float bestv = -1.0f;
#pragma unroll
        for (int cI = 0; cI < NCLS; ++cI) {
            float p = e[cI] * inv;
            out[(size_t)m * NCLS + cI] = p;
            if (p > bestv) { bestv = p; best = cI; }  // first-occurrence argmax
        }
        out[(size_t)NMTOT * NCLS + m] = (float)best;
    }
}

// ---------------------------------------------------------------------------
extern "C" void kernel_launch(void* const* d_in, const int* in_sizes, int n_in,
                              void* d_out, int out_size, void* d_ws, size_t ws_size,
                              hipStream_t stream) {
    const float* bert     = (const float*)d_in[0];
    const int*   word_ids = (const int*)d_in[1];
    const float* W_ih_f   = (const float*)d_in[2];
    const float* W_hh_f   = (const float*)d_in[3];
    const float* b_f      = (const float*)d_in[4];
    const float* W_ih_b   = (const float*)d_in[5];
    const float* W_hh_b   = (const float*)d_in[6];
    const float* b_b      = (const float*)d_in[7];
    const float* W_lin    = (const float*)d_in[8];
    const float* b_lin    = (const float*)d_in[9];
    float* out = (float*)d_out;   // f32: prob [8160*9] then path [8160]

    char* ws = (char*)d_ws;
    size_t off = 0;
    auto alloc = [&](size_t bytes) -> void* {
        void* p = ws + off;
        off += (bytes + 255) & ~(size_t)255;
        return p;
    };
    int*   rowbase = (int*)alloc((size_t)NMTOT * sizeof(int));
    float* xgf = (float*)alloc((size_t)NMTOT * NG4 * sizeof(float));   // 100 MB
    float* xgb = (float*)alloc((size_t)NMTOT * NG4 * sizeof(float));   // 100 MB
    float* hf  = (float*)alloc((size_t)NMTOT * NH * sizeof(float));    // 25 MB
    float* hb  = (float*)alloc((size_t)NMTOT * NH * sizeof(float));    // 25 MB
    float* hbuf = (float*)alloc((size_t)4 * PARSZ * sizeof(float));    // 384 KB
    float* cst  = (float*)alloc((size_t)2 * PARSZ * sizeof(float));    // 192 KB

    pool_idx_kernel<<<NB, 256, 0, stream>>>(word_ids, rowbase);

    dim3 ggrid(NG4 / 128, (NMTOT + 127) / 128, 2);
    gemm_xg_kernel<<<ggrid, 256, 0, stream>>>(bert, rowbase, W_ih_f, b_f,
                                              W_ih_b, b_b, xgf, xgb);

    // Zero recurrence state (ws is poisoned before every call).
    hipMemsetAsync(hbuf, 0, (size_t)4 * PARSZ * sizeof(float), stream);
    hipMemsetAsync(cst,  0, (size_t)2 * PARSZ * sizeof(float), stream);

    // 255 sequential per-step launches: kernel boundary = grid-wide barrier.
    const size_t lds_bytes = (size_t)16 * LROW * sizeof(float);  // 49408 B
    for (int s = 0; s < NW; ++s) {
        lstm_step_kernel<<<dim3(256), dim3(384), lds_bytes, stream>>>(
            s, xgf, xgb, W_hh_f, W_hh_b, hf, hb, hbuf, cst);
    }

    head_kernel<<<NMTOT, 64, 0, stream>>>(hf, hb, W_lin, b_lin, out);
}